// Round 8
// baseline (284.532 us; speedup 1.0000x reference)
//
#include <hip/hip_runtime.h>

#define N_NODES 100000
#define N_EDGES 1600000
#define D 128      // D_IN == D_HID
#define D_OUT 64
#define MAXDEG 64  // Poisson(16); max over 100k nodes ~35. 64 = safe pow2.

// Bucketed CSR build (multisplit) — REQUIRED for scatter write locality
// (round-1 direct atomics: 16x write amplification, WRITE 45->134MB).
#define NBUCK 782          // buckets of 128 nodes
#define BSHIFT 7
#define BCAP  3072         // avg 2046 edges/bucket, ~10 sigma slack
#define NBLK_SPLIT 1000    // was 500: ~2 blocks/CU was a parallelism bottleneck
#define CHUNK 1600         // 1000*1600 = 1.6M exact
#define NBLK_PACK 25       // 16 (Wp1) + 8 (Wp2) + 1 (zero pad rows)
#define GEMM_BLOCKS 1563   // ceil(100000/64)

typedef __attribute__((ext_vector_type(8))) short short8;   // 8 bf16 (4 VGPRs)
typedef __attribute__((ext_vector_type(4))) float floatx4;  // MFMA C/D
typedef __attribute__((ext_vector_type(2))) float floatx2;
typedef __attribute__((ext_vector_type(4))) unsigned uint32x4;

__device__ inline unsigned short f2bf(float f) {   // RNE f32 -> bf16 (cold paths)
    unsigned u = __builtin_bit_cast(unsigned, f);
    u = (u + 0x7fffu + ((u >> 16) & 1u)) >> 16;
    return (unsigned short)u;
}
__device__ inline float bf2f(unsigned u16) {
    return __builtin_bit_cast(float, u16 << 16);
}
// HW packed RNE f32x2 -> bf16x2 (1 instr vs ~8 scalar VALU ops)
__device__ inline unsigned cvt_pk_bf16(float lo, float hi) {
    unsigned r;
    asm("v_cvt_pk_bf16_f32 %0, %1, %2" : "=v"(r) : "v"(lo), "v"(hi));
    return r;
}

// ---- pack W = [Wa | Wb] (N-concat, K=128) into MFMA B-frag order ----
// KPERM: permute K-rows to consume an interleave-stored A (gemm ILV=1 output):
// packed K-position k holds original row ((k&7)<<4)|(k>>3).
template<bool KPERM>
__device__ inline void pack_ncat(const float* __restrict__ Wa, const float* __restrict__ Wb,
                                 int ncA, int ncB, unsigned short* __restrict__ out, int t) {
    int nnt = (ncA + ncB) >> 4;
    int lane = t & 63;
    int nt = (t >> 6) % nnt;
    int kt = t / (64 * nnt);                 // 0..3 (K=128)
    int col = nt * 16 + (lane & 15);
    int k0 = kt * 32 + ((lane >> 4) << 3);
    const float* W = (col < ncA) ? Wa : Wb;
    int nc = (col < ncA) ? ncA : ncB;
    int c  = (col < ncA) ? col : col - ncA;
    unsigned short* dstp = out + (size_t)((kt * nnt + nt) * 64 + lane) * 8;
    #pragma unroll
    for (int j = 0; j < 8; ++j) {
        int k = k0 + j;
        int kr = KPERM ? (((k & 7) << 4) | (k >> 3)) : k;
        dstp[j] = f2bf(W[(size_t)kr * nc + c]);
    }
}

// ------- phase A: multisplit edges into 128-node buckets ∪ weight pack ∪ pad-zero --
__global__ __launch_bounds__(256) void split_pack(
        const int* __restrict__ src, const int* __restrict__ dst,
        int* __restrict__ gcur, int* __restrict__ bucketbuf,
        const float* __restrict__ Ws1, const float* __restrict__ Wn1,
        const float* __restrict__ Ws2, const float* __restrict__ Wn2,
        unsigned short* __restrict__ Wp1, unsigned short* __restrict__ Wp2,
        unsigned char* __restrict__ y8, unsigned char* __restrict__ z8) {
    __shared__ int cnt[NBUCK];
    __shared__ int base_s[NBUCK];
    __shared__ int dstc[CHUNK];    // cache dst chunk: read HBM once, not twice
    const int tid = threadIdx.x;
    const int b = blockIdx.x;
    if (b < NBLK_SPLIT) {
        const int e0 = b * CHUNK;
        for (int i = tid; i < NBUCK; i += 256) cnt[i] = 0;
        __syncthreads();
        for (int i = tid; i < CHUNK; i += 256) {
            int d = __builtin_nontemporal_load(dst + e0 + i);
            dstc[i] = d;
            atomicAdd(&cnt[d >> BSHIFT], 1);
        }
        __syncthreads();
        for (int i = tid; i < NBUCK; i += 256) {
            int c = cnt[i];
            base_s[i] = c ? atomicAdd(&gcur[i], c) : 0;
            cnt[i] = 0;   // reuse as per-block write cursor
        }
        __syncthreads();
        for (int i = tid; i < CHUNK; i += 256) {
            int d = dstc[i];
            int s = __builtin_nontemporal_load(src + e0 + i);
            int bk = d >> BSHIFT;
            int p = base_s[bk] + atomicAdd(&cnt[bk], 1);
            if (p < BCAP)   // statically impossible overflow; safety net
                bucketbuf[bk * BCAP + p] = ((d & 127) << 17) | s;
        }
    } else {
        int sub = b - NBLK_SPLIT;
        if (sub < 16)      pack_ncat<false>(Ws1, Wn1, D, D, Wp1, sub * 256 + tid);
        else if (sub < 24) pack_ncat<true >(Ws2, Wn2, D_OUT, D_OUT, Wp2, (sub - 16) * 256 + tid);
        else {
            // zero the sentinel pad rows (gathers of CSR padding land here)
            if (tid < 32)       ((unsigned*)(y8 + (size_t)N_NODES * 128))[tid] = 0;
            else if (tid < 48)  ((unsigned*)(z8 + (size_t)N_NODES * 64))[tid - 32] = 0;
        }
    }
}

// --------------- shared GEMM body: [self+bias | nbr] = A @ [Ws | Wn], K=128 -----
// ILV=1 (layer 1, NTA=NTB=8): store position m*8+nt <- col nt*16+m; one 16B bf16
//   + one 8B fp8 store per row per lane. Wp2 is K-row-permuted to consume it.
// ILV=2 (layer 2, NTA=NTB=4): store position m*4+nt <- col nt*16+m; one 16B f32
//   + one 4B fp8 store. agg_add<L2> un-permutes at its final coalesced write.
template<int NTA, int NTB, bool AF32, int ILV>
__device__ inline void gemm_body(int bid,
        const void* __restrict__ A, const unsigned short* __restrict__ Wp,
        const float* __restrict__ bias, void* __restrict__ OutA,
        unsigned char* __restrict__ OutB, int tid)
{
    const int NT = NTA + NTB;
    const int wave = tid >> 6;
    const int lane = tid & 63;
    const int q = lane >> 4, m = lane & 15;

    int row = bid * 64 + wave * 16 + m;
    int rowc = (row < N_NODES) ? row : (N_NODES - 1);

    floatx4 acc[NT];
    #pragma unroll
    for (int nt = 0; nt < NT; ++nt) acc[nt] = (floatx4){0.f, 0.f, 0.f, 0.f};

    #pragma unroll
    for (int kt = 0; kt < 4; ++kt) {
        short8 af;
        if (AF32) {
            const float* xr = (const float*)A + (size_t)rowc * D + kt * 32 + q * 8;
            float4 f0 = *(const float4*)xr;
            float4 f1 = *(const float4*)(xr + 4);
            uint32x4 t;
            t[0] = cvt_pk_bf16(f0.x, f0.y);
            t[1] = cvt_pk_bf16(f0.z, f0.w);
            t[2] = cvt_pk_bf16(f1.x, f1.y);
            t[3] = cvt_pk_bf16(f1.z, f1.w);
            af = __builtin_bit_cast(short8, t);
        } else {
            af = *(const short8*)((const unsigned short*)A +
                                  (size_t)rowc * D + kt * 32 + q * 8);
        }
        #pragma unroll
        for (int nt = 0; nt < NT; ++nt) {
            short8 bf = *(const short8*)(Wp + (size_t)((kt * NT + nt) * 64 + lane) * 8);
            acc[nt] = __builtin_amdgcn_mfma_f32_16x16x32_bf16(af, bf, acc[nt], 0, 0, 0);
        }
    }

    const int orow_base = bid * 64 + wave * 16 + q * 4;
    if (ILV == 1) {
        float bv[8];
        #pragma unroll
        for (int nt = 0; nt < 8; ++nt) bv[nt] = bias[nt * 16 + m];
        #pragma unroll
        for (int i = 0; i < 4; ++i) {
            int orow = orow_base + i;
            if (orow < N_NODES) {
                uint32x4 pv;
                #pragma unroll
                for (int t = 0; t < 4; ++t)
                    pv[t] = cvt_pk_bf16(acc[2 * t][i]     + bv[2 * t],
                                        acc[2 * t + 1][i] + bv[2 * t + 1]);
                *(uint32x4*)((unsigned short*)OutA + (size_t)orow * 128 + m * 8) = pv;
                int pk0 = __builtin_amdgcn_cvt_pk_fp8_f32(acc[8][i],  acc[9][i],  0,   false);
                pk0     = __builtin_amdgcn_cvt_pk_fp8_f32(acc[10][i], acc[11][i], pk0, true);
                int pk1 = __builtin_amdgcn_cvt_pk_fp8_f32(acc[12][i], acc[13][i], 0,   false);
                pk1     = __builtin_amdgcn_cvt_pk_fp8_f32(acc[14][i], acc[15][i], pk1, true);
                uint2 v8; v8.x = (unsigned)pk0; v8.y = (unsigned)pk1;
                *(uint2*)(OutB + (size_t)orow * 128 + m * 8) = v8;
            }
        }
    } else {  // ILV == 2
        float bv[4];
        #pragma unroll
        for (int nt = 0; nt < 4; ++nt) bv[nt] = bias[nt * 16 + m];
        #pragma unroll
        for (int i = 0; i < 4; ++i) {
            int orow = orow_base + i;
            if (orow < N_NODES) {
                float4 o;
                o.x = acc[0][i] + bv[0]; o.y = acc[1][i] + bv[1];
                o.z = acc[2][i] + bv[2]; o.w = acc[3][i] + bv[3];
                *(float4*)((float*)OutA + (size_t)orow * 64 + m * 4) = o;
                int pk = __builtin_amdgcn_cvt_pk_fp8_f32(acc[4][i], acc[5][i], 0,  false);
                pk     = __builtin_amdgcn_cvt_pk_fp8_f32(acc[6][i], acc[7][i], pk, true);
                *(unsigned*)(OutB + (size_t)orow * 64 + m * 4) = (unsigned)pk;
            }
        }
    }
}

// -------- fused: per-bucket CSR build ∪ layer-1 GEMM (independent work) ---------
// CSR blocks FIRST in the grid: their scattered-atomic latency overlaps the MFMA
// blocks that follow, instead of forming a serial tail after them.
__global__ __launch_bounds__(256) void gemm1_csr(
        const float* __restrict__ x, const unsigned short* __restrict__ Wp1,
        const float* __restrict__ b1, unsigned short* __restrict__ xs,
        unsigned char* __restrict__ y8,
        const int* __restrict__ gcur, const int* __restrict__ bucketbuf,
        int* __restrict__ dcount, int* __restrict__ csrp)
{
    __shared__ int lcnt[128];
    const int tid = threadIdx.x;
    if (blockIdx.x < NBUCK) {
        const int b = blockIdx.x;
        if (tid < 128) lcnt[tid] = 0;
        __syncthreads();
        int m = gcur[b]; if (m > BCAP) m = BCAP;
        const int* __restrict__ buf = bucketbuf + b * BCAP;
        for (int i = tid; i < m; i += 256) {
            int v = buf[i];
            int dloc = (v >> 17) & 127, s = v & 0x1FFFF;
            int node = (b << BSHIFT) + dloc;
            int slot = atomicAdd(&lcnt[dloc], 1);
            if (slot < MAXDEG && node < N_NODES)
                csrp[((size_t)node << 6) + slot] = s;
        }
        __syncthreads();
        if (tid < 128) {
            int node = (b << BSHIFT) + tid;
            if (node < N_NODES) {
                int c = lcnt[tid]; if (c > MAXDEG) c = MAXDEG;
                dcount[node] = c;
                int cf = (c + 15) & ~15; if (cf > MAXDEG) cf = MAXDEG;
                int* row = csrp + ((size_t)node << 6);
                for (int k = c; k < cf; ++k) row[k] = N_NODES;   // sentinel -> zero row
            }
        }
    } else {
        gemm_body<8, 8, true, 1>(blockIdx.x - NBUCK, x, Wp1, b1, xs, y8, tid);
    }
}

// --------------------- layer-2 GEMM (standalone launch) -------------------------
__global__ __launch_bounds__(256) void gemm2(
        const unsigned short* __restrict__ h, const unsigned short* __restrict__ Wp2,
        const float* __restrict__ b2, float* __restrict__ tmp,
        unsigned char* __restrict__ z8)
{
    gemm_body<4, 4, false, 2>(blockIdx.x, h, Wp2, b2, tmp, z8, threadIdx.x);
}

// ---------- mean-agg + self-add: one wave per node, 4B/lane dword gathers -------
// Masked csrp read: only lanes < ceil16(dg) load their slot -> 1 cache line for
// typical deg<=16 (was 4). L1: 32 lanes/edge, fold = ONE shfl step, bf16+ReLU out.
// L2: 16 lanes/edge, fold = two steps; inputs are pi2-permuted (positional), the
// final store un-permutes: lane l writes cols {nt*16+l} -> 4 coalesced 64B runs.
template<bool L1>
__global__ __launch_bounds__(256) void agg_add(
        const unsigned char* __restrict__ feat, const int* __restrict__ csrp,
        const int* __restrict__ dcount, const void* __restrict__ self,
        void* __restrict__ out)
{
    const int LPE = L1 ? 32 : 16;      // lanes per edge (4B/lane)
    const int EPG = 64 / LPE;          // edges per load-group: 2 (L1), 4 (L2)
    const int FSH = L1 ? 7 : 6;        // log2(row bytes)
    const int NC  = L1 ? 128 : 64;     // columns

    int w = (blockIdx.x * 256 + threadIdx.x) >> 6;
    int lane = threadIdx.x & 63;
    if (w >= N_NODES) return;
    int dg = __builtin_amdgcn_readfirstlane(dcount[w]);
    int cf = (dg + 15) & ~15;          // lanes >= cf are never shfl-selected
    const int g = lane / LPE;          // edge slot within group
    const int l = lane % LPE;          // dword chunk (4 columns)
    int idxv = 0;
    if (lane < cf) idxv = csrp[((size_t)w << 6) + lane];

    floatx2 ac0 = (floatx2){0.f, 0.f};
    floatx2 ac1 = (floatx2){0.f, 0.f};
    for (int j = 0; j < dg; j += 16) {
        #pragma unroll
        for (int u = 0; u < 16 / EPG; ++u) {
            int s = __shfl(idxv, j + u * EPG + g);
            unsigned v = *(const unsigned*)(feat + ((size_t)s << FSH) + (l << 2));
            ac0 += __builtin_amdgcn_cvt_pk_f32_fp8(v, false);
            ac1 += __builtin_amdgcn_cvt_pk_f32_fp8(v, true);
        }
    }
    // fold edge-slot groups (lanes sharing l)
    #pragma unroll
    for (int delta = 32; delta >= LPE; delta >>= 1) {
        ac0.x += __shfl_down(ac0.x, delta); ac0.y += __shfl_down(ac0.y, delta);
        ac1.x += __shfl_down(ac1.x, delta); ac1.y += __shfl_down(ac1.y, delta);
    }
    if (g == 0) {                      // lanes 0..LPE-1 hold 4-col sums
        float invd = (dg > 0) ? 1.0f / (float)dg : 1.0f;
        if (L1) {                      // self bf16, out bf16 + ReLU (positional)
            uint2 sv = *(const uint2*)((const unsigned short*)self + (size_t)w * NC + l * 4);
            float h0 = bf2f(sv.x & 0xffffu)  + ac0.x * invd;
            float h1 = bf2f(sv.x >> 16)      + ac0.y * invd;
            float h2 = bf2f(sv.y & 0xffffu)  + ac1.x * invd;
            float h3 = bf2f(sv.y >> 16)      + ac1.y * invd;
            h0 = fmaxf(h0, 0.f); h1 = fmaxf(h1, 0.f);
            h2 = fmaxf(h2, 0.f); h3 = fmaxf(h3, 0.f);
            uint2 pv;
            pv.x = cvt_pk_bf16(h0, h1);
            pv.y = cvt_pk_bf16(h2, h3);
            *(uint2*)((unsigned short*)out + (size_t)w * NC + l * 4) = pv;
        } else {                       // self f32 (pi2), out f32 (identity)
            const float* sp = (const float*)self + (size_t)w * NC + l * 4;
            float4 s0 = *(const float4*)sp;
            float v0 = s0.x + ac0.x * invd;   // col l
            float v1 = s0.y + ac0.y * invd;   // col 16+l
            float v2 = s0.z + ac1.x * invd;   // col 32+l
            float v3 = s0.w + ac1.y * invd;   // col 48+l
            float* op = (float*)out + (size_t)w * NC;
            op[l]      = v0;
            op[16 + l] = v1;
            op[32 + l] = v2;
            op[48 + l] = v3;
        }
    }
}

extern "C" void kernel_launch(void* const* d_in, const int* in_sizes, int n_in,
                              void* d_out, int out_size, void* d_ws, size_t ws_size,
                              hipStream_t stream) {
    const float* x   = (const float*)d_in[0];
    const int*   src = (const int*)d_in[1];
    const int*   dst = (const int*)d_in[2];
    const float* Ws1 = (const float*)d_in[3];
    const float* Wn1 = (const float*)d_in[4];
    const float* b1  = (const float*)d_in[5];
    const float* Ws2 = (const float*)d_in[6];
    const float* Wn2 = (const float*)d_in[7];
    const float* b2  = (const float*)d_in[8];
    float* out = (float*)d_out;

    const size_t nd = (size_t)N_NODES * D;   // 12.8M elements
    unsigned short* h   = (unsigned short*)d_ws;          // bf16 hidden   25.6 MB
    unsigned short* xs  = h + nd;                         // bf16 self (L1) 25.6 MB
    float*          tmp = (float*)xs;                     // f32 self (L2), aliased
    unsigned char*  y8  = (unsigned char*)(xs + nd);      // fp8 y + pad   12.8 MB
    unsigned char*  z8  = y8 + (size_t)(N_NODES + 1) * D; // fp8 z + pad    6.4 MB
    int* dcount = (int*)(z8 + (size_t)(N_NODES + 1) * D_OUT);
    int* csrp   = dcount + N_NODES;                       // padded CSR    25.6 MB
    int* gcur   = csrp + (size_t)N_NODES * MAXDEG;        // (pad to 1024)
    int* bucketbuf = gcur + 1024;                         // bucket edges   9.6 MB
    unsigned short* Wp1 = (unsigned short*)(bucketbuf + (size_t)NBUCK * BCAP); // 64 KB
    unsigned short* Wp2 = Wp1 + 32768;                    // 32 KB

    hipMemsetAsync(gcur, 0, NBUCK * sizeof(int), stream);

    split_pack<<<NBLK_SPLIT + NBLK_PACK, 256, 0, stream>>>(
        src, dst, gcur, bucketbuf, Ws1, Wn1, Ws2, Wn2, Wp1, Wp2, y8, z8);

    const int agg_blocks = (N_NODES * 64 + 255) / 256;    // 25000

    // CSR build (first) fused with layer-1 GEMM (ILV1)
    gemm1_csr<<<NBUCK + GEMM_BLOCKS, 256, 0, stream>>>(
        x, Wp1, b1, xs, y8, gcur, bucketbuf, dcount, csrp);
    agg_add<true ><<<agg_blocks, 256, 0, stream>>>(y8, csrp, dcount, xs, h);
    // layer 2 (ILV2; Wp2 K-rows permuted to consume interleaved h)
    gemm2<<<GEMM_BLOCKS, 256, 0, stream>>>(h, Wp2, b2, tmp, z8);
    agg_add<false><<<agg_blocks, 256, 0, stream>>>(z8, csrp, dcount, tmp, out);
}

// Round 9
// 272.870 us; speedup vs baseline: 1.0427x; 1.0427x over previous
//
#include <hip/hip_runtime.h>

#define N_NODES 100000
#define N_EDGES 1600000
#define D 128      // D_IN == D_HID
#define D_OUT 64
#define MAXDEG 64  // Poisson(16); max over 100k nodes ~35. 64 = safe pow2.

// Bucketed CSR build (multisplit) — REQUIRED for scatter write locality
// (round-1 direct atomics: 16x write amplification, WRITE 45->134MB).
// 196 buckets of 512 nodes (round-9): 4x fewer gcur atomics than 782-bucket
// (98K vs 385K), 64B dense write runs; the heavier CSR blocks hide under the
// gemm MFMA blocks in the fused gemm1_csr grid.
#define NBUCK 196          // buckets of 512 nodes
#define BSHIFT 9
#define BMASK 511
#define BCAP  12288        // mean 8192 edges/bucket, +45 sigma slack
#define NBLK_SPLIT 500     // round-8's 1000 doubled gcur atomics: regression
#define CHUNK 3200         // 500*3200 = 1.6M exact
#define NBLK_PACK 25       // 16 (Wp1) + 8 (Wp2) + 1 (zero pad rows)
#define GEMM_BLOCKS 1563   // ceil(100000/64)

typedef __attribute__((ext_vector_type(8))) short short8;   // 8 bf16 (4 VGPRs)
typedef __attribute__((ext_vector_type(4))) float floatx4;  // MFMA C/D
typedef __attribute__((ext_vector_type(2))) float floatx2;
typedef __attribute__((ext_vector_type(4))) unsigned uint32x4;

__device__ inline unsigned short f2bf(float f) {   // RNE f32 -> bf16 (cold paths)
    unsigned u = __builtin_bit_cast(unsigned, f);
    u = (u + 0x7fffu + ((u >> 16) & 1u)) >> 16;
    return (unsigned short)u;
}
__device__ inline float bf2f(unsigned u16) {
    return __builtin_bit_cast(float, u16 << 16);
}
// HW packed RNE f32x2 -> bf16x2 (1 instr vs ~8 scalar VALU ops)
__device__ inline unsigned cvt_pk_bf16(float lo, float hi) {
    unsigned r;
    asm("v_cvt_pk_bf16_f32 %0, %1, %2" : "=v"(r) : "v"(lo), "v"(hi));
    return r;
}

// ---- pack W = [Wa | Wb] (N-concat, K=128) into MFMA B-frag order ----
// KPERM: permute K-rows to consume an interleave-stored A (gemm ILV=1 output):
// packed K-position k holds original row ((k&7)<<4)|(k>>3).
template<bool KPERM>
__device__ inline void pack_ncat(const float* __restrict__ Wa, const float* __restrict__ Wb,
                                 int ncA, int ncB, unsigned short* __restrict__ out, int t) {
    int nnt = (ncA + ncB) >> 4;
    int lane = t & 63;
    int nt = (t >> 6) % nnt;
    int kt = t / (64 * nnt);                 // 0..3 (K=128)
    int col = nt * 16 + (lane & 15);
    int k0 = kt * 32 + ((lane >> 4) << 3);
    const float* W = (col < ncA) ? Wa : Wb;
    int nc = (col < ncA) ? ncA : ncB;
    int c  = (col < ncA) ? col : col - ncA;
    unsigned short* dstp = out + (size_t)((kt * nnt + nt) * 64 + lane) * 8;
    #pragma unroll
    for (int j = 0; j < 8; ++j) {
        int k = k0 + j;
        int kr = KPERM ? (((k & 7) << 4) | (k >> 3)) : k;
        dstp[j] = f2bf(W[(size_t)kr * nc + c]);
    }
}

// ------- phase A: multisplit edges into 512-node buckets ∪ weight pack ∪ pad-zero --
__global__ __launch_bounds__(256) void split_pack(
        const int* __restrict__ src, const int* __restrict__ dst,
        int* __restrict__ gcur, int* __restrict__ bucketbuf,
        const float* __restrict__ Ws1, const float* __restrict__ Wn1,
        const float* __restrict__ Ws2, const float* __restrict__ Wn2,
        unsigned short* __restrict__ Wp1, unsigned short* __restrict__ Wp2,
        unsigned char* __restrict__ y8, unsigned char* __restrict__ z8) {
    __shared__ int cnt[NBUCK];
    __shared__ int base_s[NBUCK];
    __shared__ int dstc[CHUNK];    // cache dst chunk: read HBM once, not twice
    const int tid = threadIdx.x;
    const int b = blockIdx.x;
    if (b < NBLK_SPLIT) {
        const int e0 = b * CHUNK;
        for (int i = tid; i < NBUCK; i += 256) cnt[i] = 0;
        __syncthreads();
        for (int i = tid; i < CHUNK; i += 256) {
            int d = __builtin_nontemporal_load(dst + e0 + i);
            dstc[i] = d;
            atomicAdd(&cnt[d >> BSHIFT], 1);
        }
        __syncthreads();
        for (int i = tid; i < NBUCK; i += 256) {
            int c = cnt[i];
            base_s[i] = c ? atomicAdd(&gcur[i], c) : 0;
            cnt[i] = 0;   // reuse as per-block write cursor
        }
        __syncthreads();
        for (int i = tid; i < CHUNK; i += 256) {
            int d = dstc[i];
            int s = __builtin_nontemporal_load(src + e0 + i);
            int bk = d >> BSHIFT;
            int p = base_s[bk] + atomicAdd(&cnt[bk], 1);
            if (p < BCAP)   // statically impossible overflow; safety net
                bucketbuf[bk * BCAP + p] = ((d & BMASK) << 17) | s;
        }
    } else {
        int sub = b - NBLK_SPLIT;
        if (sub < 16)      pack_ncat<false>(Ws1, Wn1, D, D, Wp1, sub * 256 + tid);
        else if (sub < 24) pack_ncat<true >(Ws2, Wn2, D_OUT, D_OUT, Wp2, (sub - 16) * 256 + tid);
        else {
            // zero the sentinel pad rows (gathers of CSR padding land here)
            if (tid < 32)       ((unsigned*)(y8 + (size_t)N_NODES * 128))[tid] = 0;
            else if (tid < 48)  ((unsigned*)(z8 + (size_t)N_NODES * 64))[tid - 32] = 0;
        }
    }
}

// --------------- shared GEMM body: [self+bias | nbr] = A @ [Ws | Wn], K=128 -----
// ILV=1 (layer 1, NTA=NTB=8): store position m*8+nt <- col nt*16+m; one 16B bf16
//   + one 8B fp8 store per row per lane. Wp2 is K-row-permuted to consume it.
// ILV=2 (layer 2, NTA=NTB=4): store position m*4+nt <- col nt*16+m; one 16B f32
//   + one 4B fp8 store. agg_add<L2> un-permutes at its final coalesced write.
template<int NTA, int NTB, bool AF32, int ILV>
__device__ inline void gemm_body(int bid,
        const void* __restrict__ A, const unsigned short* __restrict__ Wp,
        const float* __restrict__ bias, void* __restrict__ OutA,
        unsigned char* __restrict__ OutB, int tid)
{
    const int NT = NTA + NTB;
    const int wave = tid >> 6;
    const int lane = tid & 63;
    const int q = lane >> 4, m = lane & 15;

    int row = bid * 64 + wave * 16 + m;
    int rowc = (row < N_NODES) ? row : (N_NODES - 1);

    floatx4 acc[NT];
    #pragma unroll
    for (int nt = 0; nt < NT; ++nt) acc[nt] = (floatx4){0.f, 0.f, 0.f, 0.f};

    #pragma unroll
    for (int kt = 0; kt < 4; ++kt) {
        short8 af;
        if (AF32) {
            const float* xr = (const float*)A + (size_t)rowc * D + kt * 32 + q * 8;
            float4 f0 = *(const float4*)xr;
            float4 f1 = *(const float4*)(xr + 4);
            uint32x4 t;
            t[0] = cvt_pk_bf16(f0.x, f0.y);
            t[1] = cvt_pk_bf16(f0.z, f0.w);
            t[2] = cvt_pk_bf16(f1.x, f1.y);
            t[3] = cvt_pk_bf16(f1.z, f1.w);
            af = __builtin_bit_cast(short8, t);
        } else {
            af = *(const short8*)((const unsigned short*)A +
                                  (size_t)rowc * D + kt * 32 + q * 8);
        }
        #pragma unroll
        for (int nt = 0; nt < NT; ++nt) {
            short8 bf = *(const short8*)(Wp + (size_t)((kt * NT + nt) * 64 + lane) * 8);
            acc[nt] = __builtin_amdgcn_mfma_f32_16x16x32_bf16(af, bf, acc[nt], 0, 0, 0);
        }
    }

    const int orow_base = bid * 64 + wave * 16 + q * 4;
    if (ILV == 1) {
        float bv[8];
        #pragma unroll
        for (int nt = 0; nt < 8; ++nt) bv[nt] = bias[nt * 16 + m];
        #pragma unroll
        for (int i = 0; i < 4; ++i) {
            int orow = orow_base + i;
            if (orow < N_NODES) {
                uint32x4 pv;
                #pragma unroll
                for (int t = 0; t < 4; ++t)
                    pv[t] = cvt_pk_bf16(acc[2 * t][i]     + bv[2 * t],
                                        acc[2 * t + 1][i] + bv[2 * t + 1]);
                *(uint32x4*)((unsigned short*)OutA + (size_t)orow * 128 + m * 8) = pv;
                int pk0 = __builtin_amdgcn_cvt_pk_fp8_f32(acc[8][i],  acc[9][i],  0,   false);
                pk0     = __builtin_amdgcn_cvt_pk_fp8_f32(acc[10][i], acc[11][i], pk0, true);
                int pk1 = __builtin_amdgcn_cvt_pk_fp8_f32(acc[12][i], acc[13][i], 0,   false);
                pk1     = __builtin_amdgcn_cvt_pk_fp8_f32(acc[14][i], acc[15][i], pk1, true);
                uint2 v8; v8.x = (unsigned)pk0; v8.y = (unsigned)pk1;
                *(uint2*)(OutB + (size_t)orow * 128 + m * 8) = v8;
            }
        }
    } else {  // ILV == 2
        float bv[4];
        #pragma unroll
        for (int nt = 0; nt < 4; ++nt) bv[nt] = bias[nt * 16 + m];
        #pragma unroll
        for (int i = 0; i < 4; ++i) {
            int orow = orow_base + i;
            if (orow < N_NODES) {
                float4 o;
                o.x = acc[0][i] + bv[0]; o.y = acc[1][i] + bv[1];
                o.z = acc[2][i] + bv[2]; o.w = acc[3][i] + bv[3];
                *(float4*)((float*)OutA + (size_t)orow * 64 + m * 4) = o;
                int pk = __builtin_amdgcn_cvt_pk_fp8_f32(acc[4][i], acc[5][i], 0,  false);
                pk     = __builtin_amdgcn_cvt_pk_fp8_f32(acc[6][i], acc[7][i], pk, true);
                *(unsigned*)(OutB + (size_t)orow * 64 + m * 4) = (unsigned)pk;
            }
        }
    }
}

// -------- fused: per-bucket CSR build ∪ layer-1 GEMM (independent work) ---------
// CSR blocks FIRST in the grid: their scattered-atomic latency overlaps the MFMA
// blocks that follow, instead of forming a serial tail after them.
__global__ __launch_bounds__(256) void gemm1_csr(
        const float* __restrict__ x, const unsigned short* __restrict__ Wp1,
        const float* __restrict__ b1, unsigned short* __restrict__ xs,
        unsigned char* __restrict__ y8,
        const int* __restrict__ gcur, const int* __restrict__ bucketbuf,
        int* __restrict__ dcount, int* __restrict__ csrp)
{
    __shared__ int lcnt[512];
    const int tid = threadIdx.x;
    if (blockIdx.x < NBUCK) {
        const int b = blockIdx.x;
        for (int i = tid; i < 512; i += 256) lcnt[i] = 0;
        __syncthreads();
        int m = gcur[b]; if (m > BCAP) m = BCAP;
        const int* __restrict__ buf = bucketbuf + b * BCAP;
        for (int i = tid; i < m; i += 256) {
            int v = buf[i];
            int dloc = (v >> 17) & BMASK, s = v & 0x1FFFF;
            int node = (b << BSHIFT) + dloc;
            int slot = atomicAdd(&lcnt[dloc], 1);
            if (slot < MAXDEG && node < N_NODES)
                csrp[((size_t)node << 6) + slot] = s;
        }
        __syncthreads();
        for (int i = tid; i < 512; i += 256) {
            int node = (b << BSHIFT) + i;
            if (node < N_NODES) {
                int c = lcnt[i]; if (c > MAXDEG) c = MAXDEG;
                dcount[node] = c;
                int cf = (c + 15) & ~15; if (cf > MAXDEG) cf = MAXDEG;
                int* row = csrp + ((size_t)node << 6);
                for (int k = c; k < cf; ++k) row[k] = N_NODES;   // sentinel -> zero row
            }
        }
    } else {
        gemm_body<8, 8, true, 1>(blockIdx.x - NBUCK, x, Wp1, b1, xs, y8, tid);
    }
}

// --------------------- layer-2 GEMM (standalone launch) -------------------------
__global__ __launch_bounds__(256) void gemm2(
        const unsigned short* __restrict__ h, const unsigned short* __restrict__ Wp2,
        const float* __restrict__ b2, float* __restrict__ tmp,
        unsigned char* __restrict__ z8)
{
    gemm_body<4, 4, false, 2>(blockIdx.x, h, Wp2, b2, tmp, z8, threadIdx.x);
}

// ---------- mean-agg + self-add: one wave per node, 4B/lane dword gathers -------
// Masked csrp read: only lanes < ceil16(dg) load their slot -> 1 cache line for
// typical deg<=16 (was 4). L1: 32 lanes/edge, fold = ONE shfl step, bf16+ReLU out.
// L2: 16 lanes/edge, fold = two steps; inputs are pi2-permuted (positional), the
// final store un-permutes: lane l writes cols {nt*16+l} -> 4 coalesced 64B runs.
template<bool L1>
__global__ __launch_bounds__(256) void agg_add(
        const unsigned char* __restrict__ feat, const int* __restrict__ csrp,
        const int* __restrict__ dcount, const void* __restrict__ self,
        void* __restrict__ out)
{
    const int LPE = L1 ? 32 : 16;      // lanes per edge (4B/lane)
    const int EPG = 64 / LPE;          // edges per load-group: 2 (L1), 4 (L2)
    const int FSH = L1 ? 7 : 6;        // log2(row bytes)
    const int NC  = L1 ? 128 : 64;     // columns

    int w = (blockIdx.x * 256 + threadIdx.x) >> 6;
    int lane = threadIdx.x & 63;
    if (w >= N_NODES) return;
    int dg = __builtin_amdgcn_readfirstlane(dcount[w]);
    int cf = (dg + 15) & ~15;          // lanes >= cf are never shfl-selected
    const int g = lane / LPE;          // edge slot within group
    const int l = lane % LPE;          // dword chunk (4 columns)
    int idxv = 0;
    if (lane < cf) idxv = csrp[((size_t)w << 6) + lane];

    floatx2 ac0 = (floatx2){0.f, 0.f};
    floatx2 ac1 = (floatx2){0.f, 0.f};
    for (int j = 0; j < dg; j += 16) {
        #pragma unroll
        for (int u = 0; u < 16 / EPG; ++u) {
            int s = __shfl(idxv, j + u * EPG + g);
            unsigned v = *(const unsigned*)(feat + ((size_t)s << FSH) + (l << 2));
            ac0 += __builtin_amdgcn_cvt_pk_f32_fp8(v, false);
            ac1 += __builtin_amdgcn_cvt_pk_f32_fp8(v, true);
        }
    }
    // fold edge-slot groups (lanes sharing l)
    #pragma unroll
    for (int delta = 32; delta >= LPE; delta >>= 1) {
        ac0.x += __shfl_down(ac0.x, delta); ac0.y += __shfl_down(ac0.y, delta);
        ac1.x += __shfl_down(ac1.x, delta); ac1.y += __shfl_down(ac1.y, delta);
    }
    if (g == 0) {                      // lanes 0..LPE-1 hold 4-col sums
        float invd = (dg > 0) ? 1.0f / (float)dg : 1.0f;
        if (L1) {                      // self bf16, out bf16 + ReLU (positional)
            uint2 sv = *(const uint2*)((const unsigned short*)self + (size_t)w * NC + l * 4);
            float h0 = bf2f(sv.x & 0xffffu)  + ac0.x * invd;
            float h1 = bf2f(sv.x >> 16)      + ac0.y * invd;
            float h2 = bf2f(sv.y & 0xffffu)  + ac1.x * invd;
            float h3 = bf2f(sv.y >> 16)      + ac1.y * invd;
            h0 = fmaxf(h0, 0.f); h1 = fmaxf(h1, 0.f);
            h2 = fmaxf(h2, 0.f); h3 = fmaxf(h3, 0.f);
            uint2 pv;
            pv.x = cvt_pk_bf16(h0, h1);
            pv.y = cvt_pk_bf16(h2, h3);
            *(uint2*)((unsigned short*)out + (size_t)w * NC + l * 4) = pv;
        } else {                       // self f32 (pi2), out f32 (identity)
            const float* sp = (const float*)self + (size_t)w * NC + l * 4;
            float4 s0 = *(const float4*)sp;
            float v0 = s0.x + ac0.x * invd;   // col l
            float v1 = s0.y + ac0.y * invd;   // col 16+l
            float v2 = s0.z + ac1.x * invd;   // col 32+l
            float v3 = s0.w + ac1.y * invd;   // col 48+l
            float* op = (float*)out + (size_t)w * NC;
            op[l]      = v0;
            op[16 + l] = v1;
            op[32 + l] = v2;
            op[48 + l] = v3;
        }
    }
}

extern "C" void kernel_launch(void* const* d_in, const int* in_sizes, int n_in,
                              void* d_out, int out_size, void* d_ws, size_t ws_size,
                              hipStream_t stream) {
    const float* x   = (const float*)d_in[0];
    const int*   src = (const int*)d_in[1];
    const int*   dst = (const int*)d_in[2];
    const float* Ws1 = (const float*)d_in[3];
    const float* Wn1 = (const float*)d_in[4];
    const float* b1  = (const float*)d_in[5];
    const float* Ws2 = (const float*)d_in[6];
    const float* Wn2 = (const float*)d_in[7];
    const float* b2  = (const float*)d_in[8];
    float* out = (float*)d_out;

    const size_t nd = (size_t)N_NODES * D;   // 12.8M elements
    unsigned short* h   = (unsigned short*)d_ws;          // bf16 hidden   25.6 MB
    unsigned short* xs  = h + nd;                         // bf16 self (L1) 25.6 MB
    float*          tmp = (float*)xs;                     // f32 self (L2), aliased
    unsigned char*  y8  = (unsigned char*)(xs + nd);      // fp8 y + pad   12.8 MB
    unsigned char*  z8  = y8 + (size_t)(N_NODES + 1) * D; // fp8 z + pad    6.4 MB
    int* dcount = (int*)(z8 + (size_t)(N_NODES + 1) * D_OUT);
    int* csrp   = dcount + N_NODES;                       // padded CSR    25.6 MB
    int* gcur   = csrp + (size_t)N_NODES * MAXDEG;        // (pad to 1024)
    int* bucketbuf = gcur + 1024;                         // bucket edges   9.6 MB
    unsigned short* Wp1 = (unsigned short*)(bucketbuf + (size_t)NBUCK * BCAP); // 64 KB
    unsigned short* Wp2 = Wp1 + 32768;                    // 32 KB

    hipMemsetAsync(gcur, 0, NBUCK * sizeof(int), stream);

    split_pack<<<NBLK_SPLIT + NBLK_PACK, 256, 0, stream>>>(
        src, dst, gcur, bucketbuf, Ws1, Wn1, Ws2, Wn2, Wp1, Wp2, y8, z8);

    const int agg_blocks = (N_NODES * 64 + 255) / 256;    // 25000

    // CSR build (first) fused with layer-1 GEMM (ILV1)
    gemm1_csr<<<NBUCK + GEMM_BLOCKS, 256, 0, stream>>>(
        x, Wp1, b1, xs, y8, gcur, bucketbuf, dcount, csrp);
    agg_add<true ><<<agg_blocks, 256, 0, stream>>>(y8, csrp, dcount, xs, h);
    // layer 2 (ILV2; Wp2 K-rows permuted to consume interleaved h)
    gemm2<<<GEMM_BLOCKS, 256, 0, stream>>>(h, Wp2, b2, tmp, z8);
    agg_add<false><<<agg_blocks, 256, 0, stream>>>(z8, csrp, dcount, tmp, out);
}